// Round 1
// baseline (450.814 us; speedup 1.0000x reference)
//
#include <hip/hip_runtime.h>

#define TPB 256

__device__ __forceinline__ float fast_tanh(float a) {
    // tanh(a) = 1 - 2/(1 + exp(2a)); saturates cleanly at +-1 for |a| large.
    float e = __expf(2.0f * a);
    float r = __builtin_amdgcn_rcpf(e + 1.0f);
    return fmaf(-2.0f, r, 1.0f);
}

__device__ __forceinline__ float fast_sig10(float h) {
    // sigmoid(10h) = 1/(1 + exp(-10h))
    float e = __expf(-10.0f * h);
    return __builtin_amdgcn_rcpf(1.0f + e);
}

// One thread handles TWO consecutive batch elements (4 recurrence chains),
// so each time step is a single coalesced float4 load + float4 store.
__global__ __launch_bounds__(TPB) void Pixel_RNNcontrol_75453985456217_kernel(
    const float* __restrict__ x,     // (T, B, 2)
    const float* __restrict__ h0,    // (1, B, 2)
    const float* __restrict__ W_ih,  // (2, 2) row-major
    const float* __restrict__ W_hh,  // (2, 2) row-major
    const float* __restrict__ b_ih,  // (2,)
    const float* __restrict__ b_hh,  // (2,)
    float* __restrict__ out,         // out (T,B,2) followed by hidden (B,2)
    int T, int B)
{
    int p = blockIdx.x * TPB + threadIdx.x;   // pair index
    int npairs = B >> 1;
    if (p >= npairs) return;

    // Uniform weights (broadcast loads, L2-resident)
    float w00 = W_ih[0], w01 = W_ih[1], w10 = W_ih[2], w11 = W_ih[3];
    float u00 = W_hh[0], u01 = W_hh[1], u10 = W_hh[2], u11 = W_hh[3];
    float bias0 = b_ih[0] + b_hh[0];
    float bias1 = b_ih[1] + b_hh[1];

    const float4* x4   = (const float4*)x;
    float4*       out4 = (float4*)out;
    const size_t stride4 = (size_t)(B >> 1);  // float4s per time step

    float4 hv = ((const float4*)h0)[p];
    float ha0 = hv.x, ha1 = hv.y;   // batch elem 2p
    float hb0 = hv.z, hb1 = hv.w;   // batch elem 2p+1

    size_t idx = (size_t)p;
    float4 xv = x4[idx];            // prefetch t=0
    for (int t = 0; t < T; ++t) {
        float4 xn;
        if (t + 1 < T) xn = x4[idx + stride4];   // prefetch next step (uniform branch)

        // pre-activations: a_j = x . W_ih[j,:] + h . W_hh[j,:] + bias_j
        float aa0 = fmaf(xv.x, w00, fmaf(xv.y, w01, fmaf(ha0, u00, fmaf(ha1, u01, bias0))));
        float aa1 = fmaf(xv.x, w10, fmaf(xv.y, w11, fmaf(ha0, u10, fmaf(ha1, u11, bias1))));
        float ab0 = fmaf(xv.z, w00, fmaf(xv.w, w01, fmaf(hb0, u00, fmaf(hb1, u01, bias0))));
        float ab1 = fmaf(xv.z, w10, fmaf(xv.w, w11, fmaf(hb0, u10, fmaf(hb1, u11, bias1))));

        ha0 = fast_tanh(aa0);
        ha1 = fast_tanh(aa1);
        hb0 = fast_tanh(ab0);
        hb1 = fast_tanh(ab1);

        float4 ov;
        ov.x = fast_sig10(ha0);
        ov.y = fast_sig10(ha1);
        ov.z = fast_sig10(hb0);
        ov.w = fast_sig10(hb1);
        out4[idx] = ov;

        idx += stride4;
        xv = xn;
    }

    // hidden state (1, B, 2) appended after out
    float4 hout;
    hout.x = ha0; hout.y = ha1; hout.z = hb0; hout.w = hb1;
    out4[(size_t)T * stride4 + (size_t)p] = hout;
}

extern "C" void kernel_launch(void* const* d_in, const int* in_sizes, int n_in,
                              void* d_out, int out_size, void* d_ws, size_t ws_size,
                              hipStream_t stream) {
    const float* x    = (const float*)d_in[0];
    const float* h0   = (const float*)d_in[1];
    const float* W_ih = (const float*)d_in[2];
    const float* W_hh = (const float*)d_in[3];
    const float* b_ih = (const float*)d_in[4];
    const float* b_hh = (const float*)d_in[5];
    float* out = (float*)d_out;

    const int BH = in_sizes[1];        // B * H  (H = 2)
    const int B  = BH / 2;
    const int T  = in_sizes[0] / (B * 2);  // I = 2

    const int npairs = B / 2;
    dim3 grid((npairs + TPB - 1) / TPB);
    Pixel_RNNcontrol_75453985456217_kernel<<<grid, TPB, 0, stream>>>(
        x, h0, W_ih, W_hh, b_ih, b_hh, out, T, B);
}